// Round 11
// baseline (220.898 us; speedup 1.0000x reference)
//
#include <hip/hip_runtime.h>

#define NROW 8192
#define INF  512
#define OUTF 256
#define M_ELEM (NROW * OUTF)   // 2,097,152 f32 per output matrix
#define NSTEP 32               // K-steps of 256

typedef __bf16 v8bf __attribute__((ext_vector_type(8)));
typedef __bf16 v4bf __attribute__((ext_vector_type(4)));
typedef float  v4f  __attribute__((ext_vector_type(4)));

__device__ __forceinline__ v8bf cvt_bf8(v4f u0, v4f u1) {
  v8bf v;
  v[0]=(__bf16)u0[0]; v[1]=(__bf16)u0[1]; v[2]=(__bf16)u0[2]; v[3]=(__bf16)u0[3];
  v[4]=(__bf16)u1[0]; v[5]=(__bf16)u1[1]; v[6]=(__bf16)u1[2]; v[7]=(__bf16)u1[3];
  return v;
}

// ---------------------------------------------------------------------------
// Kernel A: seq = feat @ W^T, bf16 MFMA, output in B-fragment-packed layout:
//   elem(m,o) -> (((m>>5)*16 + (o>>4))*64 + ((m>>3)&3)*16 + (o&15))*8 + (m&7)
// ---------------------------------------------------------------------------
__global__ __launch_bounds__(256) void seq_fts_kernel(
    const float* __restrict__ feat, const float* __restrict__ W,
    __bf16* __restrict__ Bp) {
  const int tid  = threadIdx.x;
  const int lane = tid & 63, w = tid >> 6;
  const int llo  = lane & 15, lhi = lane >> 4;
  const int row0 = blockIdx.x * 64;
  const int col0 = w * 64;

  v4f acc[4][4] = {};
#pragma unroll 1
  for (int kb = 0; kb < INF / 32; ++kb) {
    const int kofs = kb * 32 + lhi * 8;
    v8bf a[4], b[4];
#pragma unroll
    for (int i = 0; i < 4; ++i) {
      const float* p = feat + (size_t)(row0 + i * 16 + llo) * INF + kofs;
      a[i] = cvt_bf8(*(const v4f*)p, *(const v4f*)(p + 4));
    }
#pragma unroll
    for (int i = 0; i < 4; ++i) {
      const float* p = W + (size_t)(col0 + i * 16 + llo) * INF + kofs;
      b[i] = cvt_bf8(*(const v4f*)p, *(const v4f*)(p + 4));
    }
#pragma unroll
    for (int ri = 0; ri < 4; ++ri)
#pragma unroll
      for (int ci = 0; ci < 4; ++ci)
        acc[ri][ci] = __builtin_amdgcn_mfma_f32_16x16x32_bf16(
            a[ri], b[ci], acc[ri][ci], 0, 0, 0);
  }
#pragma unroll
  for (int ri = 0; ri < 4; ++ri)
#pragma unroll
    for (int ci = 0; ci < 4; ++ci) {
      const int mf = row0 + ri * 16 + lhi * 4;
      const int o  = col0 + ci * 16 + llo;
      size_t e = (((size_t)(mf >> 5) * 16 + (o >> 4)) * 64 +
                  ((mf >> 3) & 3) * 16 + (o & 15)) * 8 + (mf & 7);
      v4bf v;
      v[0] = (__bf16)acc[ri][ci][0]; v[1] = (__bf16)acc[ri][ci][1];
      v[2] = (__bf16)acc[ri][ci][2]; v[3] = (__bf16)acc[ri][ci][3];
      *(v4bf*)(Bp + e) = v;
    }
}

// ---------------------------------------------------------------------------
// Kernel B: out = prelu(adj @ seq + bias).
// R9's proven ingredients (1 KB contiguous adj rows, NT, XOR-swizzle via
// pre-swizzled source, B-first FIFO) + the ONE new variable: BM=32 with
// 4 waves and a 2x32KB LDS pipeline -> TWO independent blocks per CU.
// While one block sits in its vmcnt(0)+barrier drain, the co-resident
// block computes: the CU memory pipe never goes idle (kills the per-step
// sawtooth that R9/R10's single-block-per-CU structure exposed).
// ---------------------------------------------------------------------------
__global__ __launch_bounds__(256) void gcn_agg_kernel(
    const float* __restrict__ adjA, const float* __restrict__ adjB,
    const __bf16* __restrict__ Bp, const float* __restrict__ bias,
    const float* __restrict__ prelu_a, float* __restrict__ out) {
  const int tid  = threadIdx.x;
  const int lane = tid & 63, w = tid >> 6;      // 4 waves
  const int llo  = lane & 15, lhi = lane >> 4;
  const int row0 = blockIdx.x * 32;
  const int z    = blockIdx.y;
  const float* __restrict__ adj = z ? adjB : adjA;

  __shared__ __align__(16) char LdsA[2][32768];   // 2 x (32 rows x 1 KB)

  v4f acc[2][4] = {};   // [rt 0..1][ci 0..3]; wave w owns cols [w*64,(w+1)*64)

  // --- A staging: 8 instr/wave, each = one row's 1 KB contiguous chunk (NT).
  // LDS row r slot p (16B units) holds source slot p ^ key(r).
  auto stage_a = [&](int buf, int t) {
#pragma unroll
    for (int i = 0; i < 8; ++i) {
      const int r   = w * 8 + i;
      const int key = ((r & 15) << 1) | ((r >> 3) & 1);
      const float* src =
          adj + (size_t)(row0 + r) * NROW + t * 256 + ((lane ^ key) << 2);
      __builtin_amdgcn_global_load_lds(
          (const __attribute__((address_space(1))) void*)src,
          (__attribute__((address_space(3))) void*)(&LdsA[buf][r * 1024]),
          16, 0, 2 /* NT */);
    }
  };

  // --- B fragments for one step: [8 kk][4 ci], register-resident (128 VGPR).
  const __bf16* __restrict__ Bpw = Bp + ((size_t)(w * 4) * 64 + lane) * 8;
  v8bf b[8][4];
  auto load_b = [&](int t) {
#pragma unroll
    for (int kk = 0; kk < 8; ++kk)
#pragma unroll
      for (int ci = 0; ci < 4; ++ci)
        b[kk][ci] =
            *(const v8bf*)(Bpw + ((size_t)((t * 8 + kk) * 16 + ci)) * 512);
  };

  auto compute = [&](int buf) {
    const char* ab = &LdsA[buf][0];
#pragma unroll
    for (int kk = 0; kk < 8; ++kk) {
      v8bf af[2];
#pragma unroll
      for (int rt = 0; rt < 2; ++rt) {
        const int r   = rt * 16 + llo;
        const int key = ((r & 15) << 1) | ((r >> 3) & 1);
        const char* base = ab + r * 1024;
        v4f u0 = *(const v4f*)(base + (((kk * 8 + lhi * 2    ) ^ key) << 4));
        v4f u1 = *(const v4f*)(base + (((kk * 8 + lhi * 2 + 1) ^ key) << 4));
        af[rt] = cvt_bf8(u0, u1);
      }
#pragma unroll
      for (int ci = 0; ci < 4; ++ci)
#pragma unroll
        for (int rt = 0; rt < 2; ++rt)
          acc[rt][ci] = __builtin_amdgcn_mfma_f32_16x16x32_bf16(
              af[rt], b[kk][ci], acc[rt][ci], 0, 0, 0);
    }
  };

  stage_a(0, 0);

#pragma unroll 1
  for (int t = 0; t < NSTEP; ++t) {
    // Only A(t)'s 8 loads are outstanding here (B(t-1) retired by its
    // compute waits, which were vmcnt(>=8) thanks to B-before-A order).
    asm volatile("s_waitcnt vmcnt(0)" ::: "memory");
    __builtin_amdgcn_s_barrier();
    load_b(t);                                        // oldest in FIFO
    __builtin_amdgcn_sched_barrier(0);
    if (t + 1 < NSTEP) stage_a((t + 1) & 1, t + 1);   // newest in FIFO
    __builtin_amdgcn_sched_barrier(0);
    compute(t & 1);   // B-waits are vmcnt(>=8): A(t+1) never drained
  }

  // epilogue: bias + prelu, direct store
  const float slope = prelu_a[0];
  float* __restrict__ outp = out + (size_t)z * M_ELEM;
#pragma unroll
  for (int ci = 0; ci < 4; ++ci) {
    const int o  = w * 64 + ci * 16 + llo;
    const float bs = bias[o];
#pragma unroll
    for (int rt = 0; rt < 2; ++rt) {
      const int m = row0 + rt * 16 + lhi * 4;
#pragma unroll
      for (int r = 0; r < 4; ++r) {
        float v = acc[rt][ci][r] + bs;
        outp[(size_t)(m + r) * OUTF + o] = v >= 0.f ? v : slope * v;
      }
    }
  }
}

extern "C" void kernel_launch(void* const* d_in, const int* in_sizes, int n_in,
                              void* d_out, int out_size, void* d_ws, size_t ws_size,
                              hipStream_t stream) {
  const float* feat = (const float*)d_in[0];
  const float* adj  = (const float*)d_in[1];
  const float* aug  = (const float*)d_in[2];
  const float* W    = (const float*)d_in[3];
  const float* bias = (const float*)d_in[4];
  const float* pa   = (const float*)d_in[5];
  float* out = (float*)d_out;
  __bf16* Bp = (__bf16*)d_ws;                    // 4 MB packed seq_fts

  seq_fts_kernel<<<dim3(NROW / 64), 256, 0, stream>>>(feat, W, Bp);
  gcn_agg_kernel<<<dim3(NROW / 32, 2), 256, 0, stream>>>(
      adj, aug, Bp, bias, pa, out);
}